// Round 1
// baseline (372.018 us; speedup 1.0000x reference)
//
#include <hip/hip_runtime.h>
#include <math.h>

// Problem constants (B=1)
#define S_LEN 2048
#define D_DIM 512
#define H_NUM 8
#define HD    64
#define C_NUM 32
#define TOPK  5
#define SCALE 0.125f   // hd^-0.5 = 64^-0.5

// ---------------------------------------------------------------------------
// GEMM: C[M,N] = A[M,K] @ B[K,N], fp32 vector-ALU (no fp32 MFMA on CDNA4).
// 64x64 block tile, BK=32, 256 threads, 4x4 micro-tile per thread.
// ---------------------------------------------------------------------------
#define BM 64
#define BN 64
#define BK 32

__global__ __launch_bounds__(256) void gemm64(const float* __restrict__ A,
                                              const float* __restrict__ B,
                                              float* __restrict__ C,
                                              int M, int N, int K) {
    // As transposed [k][m], padded to 68 floats (keeps 16B alignment of rows,
    // 68%32=4 keeps read banks spread)
    __shared__ float As[BK][BM + 4];
    __shared__ float Bs[BK][BN];

    const int t  = threadIdx.x;
    const int tx = t & 15;     // n-dir
    const int ty = t >> 4;     // m-dir
    const int m0 = blockIdx.y * BM;
    const int n0 = blockIdx.x * BN;

    float4 acc0 = make_float4(0.f,0.f,0.f,0.f);
    float4 acc1 = make_float4(0.f,0.f,0.f,0.f);
    float4 acc2 = make_float4(0.f,0.f,0.f,0.f);
    float4 acc3 = make_float4(0.f,0.f,0.f,0.f);

    const int ar = t >> 3;        // 0..31
    const int ac = (t & 7) * 4;   // 0..28
    const int br = t >> 4;        // 0..15
    const int bc = (t & 15) * 4;  // 0..60

    for (int k0 = 0; k0 < K; k0 += BK) {
        float4 a0 = *(const float4*)&A[(size_t)(m0 + ar)      * K + k0 + ac];
        float4 a1 = *(const float4*)&A[(size_t)(m0 + ar + 32) * K + k0 + ac];
        float4 b0 = *(const float4*)&B[(size_t)(k0 + br)      * N + n0 + bc];
        float4 b1 = *(const float4*)&B[(size_t)(k0 + br + 16) * N + n0 + bc];

        __syncthreads();  // previous iteration's LDS reads done
        As[ac+0][ar]    = a0.x; As[ac+1][ar]    = a0.y; As[ac+2][ar]    = a0.z; As[ac+3][ar]    = a0.w;
        As[ac+0][ar+32] = a1.x; As[ac+1][ar+32] = a1.y; As[ac+2][ar+32] = a1.z; As[ac+3][ar+32] = a1.w;
        *(float4*)&Bs[br][bc]      = b0;
        *(float4*)&Bs[br + 16][bc] = b1;
        __syncthreads();

        #pragma unroll
        for (int kk = 0; kk < BK; ++kk) {
            float4 a = *(const float4*)&As[kk][ty * 4];
            float4 b = *(const float4*)&Bs[kk][tx * 4];
            acc0.x += a.x*b.x; acc0.y += a.x*b.y; acc0.z += a.x*b.z; acc0.w += a.x*b.w;
            acc1.x += a.y*b.x; acc1.y += a.y*b.y; acc1.z += a.y*b.z; acc1.w += a.y*b.w;
            acc2.x += a.z*b.x; acc2.y += a.z*b.y; acc2.z += a.z*b.z; acc2.w += a.z*b.w;
            acc3.x += a.w*b.x; acc3.y += a.w*b.y; acc3.z += a.w*b.z; acc3.w += a.w*b.w;
        }
    }

    *(float4*)&C[(size_t)(m0 + ty*4 + 0) * N + n0 + tx*4] = acc0;
    *(float4*)&C[(size_t)(m0 + ty*4 + 1) * N + n0 + tx*4] = acc1;
    *(float4*)&C[(size_t)(m0 + ty*4 + 2) * N + n0 + tx*4] = acc2;
    *(float4*)&C[(size_t)(m0 + ty*4 + 3) * N + n0 + tx*4] = acc3;
}

// ---------------------------------------------------------------------------
// chunk_keys[c][dcol] = mean over 64 rows of K[(c*64+r)][dcol]; ck is [32][512]
// ---------------------------------------------------------------------------
__global__ __launch_bounds__(256) void chunk_keys_kernel(const float* __restrict__ K,
                                                         float* __restrict__ ck) {
    int i = blockIdx.x * 256 + threadIdx.x;    // 0..16383
    int c = i >> 9;
    int d = i & 511;
    const float* p = K + (size_t)c * 64 * D_DIM + d;
    float sum = 0.f;
    #pragma unroll
    for (int r = 0; r < 64; ++r) sum += p[(size_t)r * D_DIM];
    ck[(size_t)c * D_DIM + d] = sum * (1.0f / 64.0f);
}

// ---------------------------------------------------------------------------
// Routing: per (s): threads t = h*32+c compute sims[h][c] = (Q_hs . ck_hc)*scale,
// then 8 threads do serial top-5 (strict > scan == jax top_k tie-breaking).
// idx layout: [(h*S + s)*5 + k]
// ---------------------------------------------------------------------------
__global__ __launch_bounds__(256) void route_topk(const float* __restrict__ Q,
                                                  const float* __restrict__ ck,
                                                  int* __restrict__ idx) {
    int s = blockIdx.x;
    int t = threadIdx.x;
    int h = t >> 5;
    int c = t & 31;

    __shared__ float qrow[D_DIM];
    __shared__ float sims[256];

    if (t < 128) {
        float4 v = *(const float4*)&Q[(size_t)s * D_DIM + t * 4];
        *(float4*)&qrow[t * 4] = v;
    }
    __syncthreads();

    const float* ckrow = ck + (size_t)c * D_DIM + h * HD;
    const float* qh    = qrow + h * HD;
    float acc = 0.f;
    #pragma unroll
    for (int d = 0; d < HD; d += 4) {
        float4 cv = *(const float4*)&ckrow[d];
        acc += qh[d+0]*cv.x + qh[d+1]*cv.y + qh[d+2]*cv.z + qh[d+3]*cv.w;
    }
    sims[t] = acc * SCALE;
    __syncthreads();

    if (t < H_NUM) {
        float* sv = &sims[t * 32];
        int* op = idx + ((size_t)t * S_LEN + s) * TOPK;
        #pragma unroll
        for (int k = 0; k < TOPK; ++k) {
            float best = -INFINITY;
            int bi = 0;
            for (int cc = 0; cc < C_NUM; ++cc) {
                float x = sv[cc];
                if (x > best) { best = x; bi = cc; }
            }
            op[k] = bi;
            sv[bi] = -INFINITY;
        }
    }
}

// ---------------------------------------------------------------------------
// Sparse chunk attention. One wave per (h,s). Online softmax over 5 chunks.
// Phase A (lane = key position l in chunk): scores = q . K_row, wave max/sum.
// Phase B (lane = (jo = l>>4 row group, dv = (l&15)*4 col group)): PV accum.
// O layout [S, D] matching final GEMM input.
// ---------------------------------------------------------------------------
__global__ __launch_bounds__(256) void moc_attn(const float* __restrict__ Q,
                                                const float* __restrict__ K,
                                                const float* __restrict__ V,
                                                const int* __restrict__ idx,
                                                float* __restrict__ O) {
    __shared__ float qbuf[4][HD];
    __shared__ float pbuf[4][HD];

    const int t    = threadIdx.x;
    const int widx = t >> 6;
    const int l    = t & 63;
    const int w    = blockIdx.x * 4 + widx;
    const int s    = w >> 3;
    const int h    = w & 7;

    // stage q row (coalesced), then hoist into registers (broadcast LDS reads)
    qbuf[widx][l] = Q[(size_t)s * D_DIM + h * HD + l];
    __syncthreads();
    float4 qr[16];
    #pragma unroll
    for (int i = 0; i < 16; ++i) qr[i] = *(const float4*)&qbuf[widx][i * 4];

    float m = -INFINITY;
    float lsum = 0.f;
    float4 acc = make_float4(0.f,0.f,0.f,0.f);
    const int jo = l >> 4;          // 0..3 -> handles rows jo*16 .. jo*16+15
    const int dv = (l & 15) * 4;    // 0..60

    const int* idxp = idx + ((size_t)h * S_LEN + s) * TOPK;

    for (int k = 0; k < TOPK; ++k) {
        int c = idxp[k];
        const float* Kb = K + ((size_t)c * 64) * D_DIM + h * HD;
        const float* Vb = V + ((size_t)c * 64) * D_DIM + h * HD;

        // ---- scores: lane l = position in chunk ----
        float sc = 0.f;
        #pragma unroll
        for (int i = 0; i < 16; ++i) {
            float4 kv = *(const float4*)&Kb[(size_t)l * D_DIM + i * 4];
            sc += qr[i].x*kv.x + qr[i].y*kv.y + qr[i].z*kv.z + qr[i].w*kv.w;
        }
        sc *= SCALE;

        float cmax = sc;
        #pragma unroll
        for (int off = 32; off > 0; off >>= 1)
            cmax = fmaxf(cmax, __shfl_xor(cmax, off, 64));
        float mnew = fmaxf(m, cmax);
        float alpha = __expf(m - mnew);      // first iter: exp(-inf)=0
        float p = __expf(sc - mnew);
        float psum = p;
        #pragma unroll
        for (int off = 32; off > 0; off >>= 1)
            psum += __shfl_xor(psum, off, 64);
        lsum = lsum * alpha + psum;
        m = mnew;
        acc.x *= alpha; acc.y *= alpha; acc.z *= alpha; acc.w *= alpha;

        pbuf[widx][l] = p;
        __syncthreads();   // waves have identical trip counts -> barriers align

        // ---- PV: lane group jo covers rows jo*16..jo*16+15, cols dv..dv+3 ----
        #pragma unroll
        for (int jj4 = 0; jj4 < 4; ++jj4) {
            int j = jo * 16 + jj4 * 4;
            float4 p4 = *(const float4*)&pbuf[widx][j];
            float4 v0 = *(const float4*)&Vb[(size_t)(j+0) * D_DIM + dv];
            float4 v1 = *(const float4*)&Vb[(size_t)(j+1) * D_DIM + dv];
            float4 v2 = *(const float4*)&Vb[(size_t)(j+2) * D_DIM + dv];
            float4 v3 = *(const float4*)&Vb[(size_t)(j+3) * D_DIM + dv];
            acc.x += p4.x*v0.x + p4.y*v1.x + p4.z*v2.x + p4.w*v3.x;
            acc.y += p4.x*v0.y + p4.y*v1.y + p4.z*v2.y + p4.w*v3.y;
            acc.z += p4.x*v0.z + p4.y*v1.z + p4.z*v2.z + p4.w*v3.z;
            acc.w += p4.x*v0.w + p4.y*v1.w + p4.z*v2.w + p4.w*v3.w;
        }
        __syncthreads();   // before next iteration overwrites pbuf
    }

    // reduce partial PV sums across the 4 jo groups (lanes l%16 + 16*jo)
    acc.x += __shfl_xor(acc.x, 16, 64);
    acc.y += __shfl_xor(acc.y, 16, 64);
    acc.z += __shfl_xor(acc.z, 16, 64);
    acc.w += __shfl_xor(acc.w, 16, 64);
    acc.x += __shfl_xor(acc.x, 32, 64);
    acc.y += __shfl_xor(acc.y, 32, 64);
    acc.z += __shfl_xor(acc.z, 32, 64);
    acc.w += __shfl_xor(acc.w, 32, 64);

    if (l < 16) {
        float inv = 1.0f / lsum;
        float4 o = make_float4(acc.x*inv, acc.y*inv, acc.z*inv, acc.w*inv);
        *(float4*)&O[(size_t)s * D_DIM + h * HD + l * 4] = o;
    }
}

// ---------------------------------------------------------------------------
extern "C" void kernel_launch(void* const* d_in, const int* in_sizes, int n_in,
                              void* d_out, int out_size, void* d_ws, size_t ws_size,
                              hipStream_t stream) {
    const float* x  = (const float*)d_in[0];
    const float* Wq = (const float*)d_in[1];
    const float* Wk = (const float*)d_in[2];
    const float* Wv = (const float*)d_in[3];
    const float* Wo = (const float*)d_in[4];
    float* out = (float*)d_out;

    const size_t SD = (size_t)S_LEN * D_DIM;   // 1048576
    float* ws   = (float*)d_ws;
    float* Qb   = ws;
    float* Kb   = Qb + SD;
    float* Vb   = Kb + SD;
    float* Ob   = Vb + SD;                     // attention output [S,D]
    float* ck   = Ob + SD;                     // [32][512]
    int*   idxb = (int*)(ck + C_NUM * D_DIM);  // [H][S][5]

    dim3 ggrid(D_DIM / BN, S_LEN / BM);        // (8, 32)

    gemm64<<<ggrid, 256, 0, stream>>>(x, Wq, Qb, S_LEN, D_DIM, D_DIM);
    gemm64<<<ggrid, 256, 0, stream>>>(x, Wk, Kb, S_LEN, D_DIM, D_DIM);
    gemm64<<<ggrid, 256, 0, stream>>>(x, Wv, Vb, S_LEN, D_DIM, D_DIM);

    chunk_keys_kernel<<<(C_NUM * D_DIM) / 256, 256, 0, stream>>>(Kb, ck);
    route_topk<<<S_LEN, 256, 0, stream>>>(Qb, ck, idxb);

    moc_attn<<<(H_NUM * S_LEN) / 4, 256, 0, stream>>>(Qb, Kb, Vb, idxb, Ob);

    gemm64<<<ggrid, 256, 0, stream>>>(Ob, Wo, out, S_LEN, D_DIM, D_DIM);
}